// Round 3
// baseline (325.929 us; speedup 1.0000x reference)
//
#include <hip/hip_runtime.h>
#include <stdint.h>

// ---------------------------------------------------------------------------
// Equivariant conv = self-connection (folded into center tap) + sparse-tap
// implicit-GEMM bf16 MFMA conv. R3: 4 waves x (8m x 4n) register blocking
// (42.7 FLOP per LDS byte vs 32 before); prep kernels merged.
// ---------------------------------------------------------------------------

#define NT_REAL 179   // taps with d^2 <= 12 (radial shells vanish beyond r=3.5)
#define NT_PAD  180
#define NGRP    45    // NT_PAD/4 taps per MFMA k-step

typedef short s16x8 __attribute__((ext_vector_type(8)));
typedef float f32x4 __attribute__((ext_vector_type(4)));

struct Taps {
  int n;
  short dl16[NT_PAD];                       // (dz*14+dy)*16 + dx (halo slot offset)
  unsigned char dz[NT_PAD], dy[NT_PAD], dx[NT_PAD];
};
constexpr Taps mk_taps() {
  Taps t{};
  t.n = 0;
  for (int a = 0; a < 7; ++a)
    for (int b = 0; b < 7; ++b)
      for (int c = 0; c < 7; ++c) {
        int d2 = (a-3)*(a-3) + (b-3)*(b-3) + (c-3)*(c-3);
        if (d2 <= 12) {
          t.dz[t.n] = (unsigned char)a; t.dy[t.n] = (unsigned char)b;
          t.dx[t.n] = (unsigned char)c;
          t.dl16[t.n] = (short)((a*14 + b)*16 + c);
          ++t.n;
        }
      }
  for (int i = t.n; i < NT_PAD; ++i) {      // pad tap: zero weights, valid addr
    t.dz[i] = 3; t.dy[i] = 3; t.dx[i] = 3; t.dl16[i] = t.dl16[0];
  }
  return t;
}
__device__ constexpr Taps TAPS = mk_taps();
static_assert(mk_taps().n == NT_REAL, "tap count");

static __device__ inline unsigned short f2bf(float f) {   // RNE fp32->bf16
  unsigned int u = __float_as_uint(f);
  unsigned int r = u + 0x7FFFu + ((u >> 16) & 1u);
  return (unsigned short)(r >> 16);
}

__device__ __forceinline__ void gl_lds16(const void* g, void* s) {
  // async 16B/lane global->LDS; LDS dest = wave-uniform base + lane*16
  __builtin_amdgcn_global_load_lds(
      (const __attribute__((address_space(1))) void*)g,
      (__attribute__((address_space(3))) void*)s, 16, 0, 0);
}

// ---------------------------------------------------------------------------
// prep kernel: blocks [0,4232) = pad/convert x -> Xp ; blocks [4232,4412) =
// build conv weights Bwp (bf16 B-operand layout, self-connection folded into
// center tap).
//   Xp [2][46][46][46][64] bf16, zero-padded channel-last.
//   Bwp[chunk8][grp45][nt4][q4][n16][j8]: MFMA k = q*8+j <-> (tap=grp*4+q,
//   ich=chunk*8+j); och = nt*16+n. Lane (q,n) fragment at byte (q*16+n)*16.
// ---------------------------------------------------------------------------
__global__ void prep(const float* __restrict__ x, const float* __restrict__ scw0,
                     const float* __restrict__ scw1, const float* __restrict__ tpw,
                     unsigned short* __restrict__ Xp, unsigned short* __restrict__ Bwp) {
  __shared__ float buf[46 * 65];            // pad: transpose buf; build: wsm alias
  int tid = threadIdx.x;

  if (blockIdx.x < 4232) {                  // ---- pad/convert ----
    int blk = blockIdx.x;                   // (b*46 + zp)*46 + yp
    int yp = blk % 46; int t = blk / 46; int zp = t % 46; int b = t / 46;
    int iz = zp - 3, iy = yp - 3;
    bool rowin = ((unsigned)iz < 40u) && ((unsigned)iy < 40u);
    if (rowin) {
      const float* src = x + (size_t)b * 4096000 + (size_t)iz * 1600 + (size_t)iy * 40;
      for (int e = tid; e < 64 * 46; e += 256) {
        int ch = e / 46, xp = e - ch * 46;
        int ix = xp - 3;
        float v = ((unsigned)ix < 40u) ? src[(size_t)ch * 64000 + ix] : 0.0f;
        buf[xp * 65 + ch] = v;
      }
    }
    __syncthreads();
    for (int f = tid; f < 46 * 8; f += 256) {
      int xp = f >> 3, g = f & 7;
      s16x8 v = s16x8{0, 0, 0, 0, 0, 0, 0, 0};
      if (rowin) {
        #pragma unroll
        for (int j = 0; j < 8; ++j) v[j] = (short)f2bf(buf[xp * 65 + g * 8 + j]);
      }
      *reinterpret_cast<s16x8*>(Xp + ((size_t)blk * 46 + xp) * 64 + g * 8) = v;
    }
    return;
  }

  // ---- build weights ----
  int t = blockIdx.x - 4232;                // 0..179
  float (*wsm)[16][16] = reinterpret_cast<float (*)[16][16]>(buf);

  int dz = TAPS.dz[t], dy = TAPS.dy[t], dx = TAPS.dx[t];
  float fz = dz - 3.0f, fy = dy - 3.0f, fx = dx - 3.0f;
  float d2 = fz*fz + fy*fy + fx*fx;
  float r = sqrtf(d2);

  const float step = 3.5f / 9.0f;
  const float Cc = 1.14136f * 7.38905609893065f;   // 1.14136 * e^2
  float emb[8];
  for (int bb = 0; bb < 8; ++bb) {
    float diff = (r - step * (bb + 1)) / step;
    float t1 = diff + 1.0f, t2 = 1.0f - diff;
    float u1 = (t1 > 0.0f) ? expf(-1.0f / t1) : 0.0f;
    float u2 = (t2 > 0.0f) ? expf(-1.0f / t2) : 0.0f;
    emb[bb] = Cc * u1 * u2;
  }

  int u = tid >> 4, o = tid & 15;
  for (int p = 0; p < 5; ++p) {
    float acc = 0.0f;
    int nidx = (p * 16 + u) * 16 + o;
    for (int bb = 0; bb < 8; ++bb) acc += emb[bb] * tpw[bb * 1280 + nidx];
    wsm[p][u][o] = acc * (1.0f / 343.0f);
  }
  __syncthreads();

  float invr = (d2 > 0.0f) ? (1.7320508075688772f / r) : 0.0f;  // sqrt(3)/r
  float sh[3] = { fz * invr, fy * invr, fx * invr };

  bool center = (dz == 3 && dy == 3 && dx == 3);
  bool padt = (t >= NT_REAL);
  const float c1 = 0.17677669529663687f;   // sqrt(1/32)
  const float c2 = 0.10206207261596575f;   // c1/sqrt(3)
  const float c3 = 0.14433756729740643f;   // 0.25/sqrt(3)
  const float c4 = 0.14433756729740643f;
  const float c5 = 0.10206207261596575f;   // 0.25/sqrt(6)
  const float inv = 0.25f;                 // 1/sqrt(MUL)

  for (int e = tid; e < 4096; e += 256) {
    int ich = e & 63, och = e >> 6;
    float v = 0.0f;
    if (!padt) {
      if (och < 16) {
        if (ich < 16) {                               // scalar->scalar
          v = c1 * wsm[0][ich][och];
          if (center) v += inv * scw0[ich * 16 + och];
        } else {                                      // vector->scalar
          int qq = ich - 16; int uu = qq / 3, ii = qq % 3;
          v = c2 * sh[ii] * wsm[1][uu][och];
        }
      } else {
        int qo = och - 16; int oo = qo / 3, kk = qo % 3;
        if (ich < 16) {                               // scalar->vector
          v = c3 * sh[kk] * wsm[2][ich][oo];
        } else {                                      // vector->vector
          int qi = ich - 16; int uu = qi / 3, ii = qi % 3;
          if (ii == kk) {
            v = c4 * wsm[3][uu][oo];
            if (center) v += inv * scw1[uu * 16 + oo];
          } else {
            int jj = 3 - ii - kk;
            float sgn = (((kk - ii + 3) % 3) == 2) ? 1.0f : -1.0f;
            v = c5 * sgn * sh[jj] * wsm[4][uu][oo];
          }
        }
      }
    }
    int chunk = ich >> 3, j = ich & 7, q = t & 3, grp = t >> 2;
    int nt = och >> 4, n = och & 15;
    size_t idx = (((((size_t)chunk * NGRP + grp) * 4 + nt) * 4 + q) * 16 + n) * 8 + j;
    Bwp[idx] = f2bf(v);
  }
}

// ---------------------------------------------------------------------------
// conv3d: implicit-GEMM. Block = 256 thr (4 waves), tile = 512 output
// positions (8z x 8y x 8x) x 64 och. Wave w owns z-planes {2w, 2w+1}:
// 8 m-tiles x 4 n-tiles per wave -> 12 ds_read_b128 per 32 MFMA (42.7 FLOP/B).
// Pipeline: 72 steps (8 ich-chunks x 9 segments of 5 tap-groups); halo and B
// double-buffered, staged async (global_load_lds) right after each barrier so
// the barrier drain is covered by a full compute step.
// LDS: halo 2 x (14*14*16 slots x 16B = 50176) + B 2 x 20480 = 141312 B.
// ---------------------------------------------------------------------------
__global__ __launch_bounds__(256) void conv3d(
    const unsigned short* __restrict__ Xp,   // [2][46][46][46][64] bf16
    const unsigned short* __restrict__ Bwp,  // [8][45][4][4][16][8] bf16
    float* __restrict__ out) {               // [2][64][40][40][40] fp32
  __shared__ __align__(16) unsigned char smem[141312];
  unsigned char* XH = smem;                  // 2 x 50176
  unsigned char* BB = smem + 100352;         // 2 x 20480

  int blk = blockIdx.x;                      // 256 blocks, 6 dummies
  int p = ((blk & 7) << 5) | (blk >> 3);     // XCD-contiguous tile ranges
  if (p >= 250) return;
  int b = p / 125; int rem = p - b * 125;
  int tz = rem / 25, ty = (rem / 5) % 5, tx = rem % 5;

  int tid = threadIdx.x;
  int lane = tid & 63;
  int w = tid >> 6;                          // wave 0..3 -> z-planes {2w,2w+1}
  int q = lane >> 4, n = lane & 15;

  const unsigned char* xg = (const unsigned char*)Xp
      + (size_t)(((b * 46 + tz * 8) * 46 + ty * 8) * 46 + tx * 8) * 128;

  // A fragment base slot: z-plane 2w (z stride 224 slots), y_rel = n>>3, x = n&7
  int abase = w * 448 + ((n >> 3) << 4) + (n & 7);

  f32x4 acc[8][4];
  #pragma unroll
  for (int a = 0; a < 8; ++a)
    #pragma unroll
    for (int nt = 0; nt < 4; ++nt) acc[a][nt] = f32x4{0.f, 0.f, 0.f, 0.f};

  // ---- async staging (per-wave slices; each instr = 64 lanes x 16B = 1KB) --
  auto stageB = [&](int c, int s, unsigned char* dst) {
    const unsigned char* bg = (const unsigned char*)Bwp
        + ((size_t)c * NGRP + s * 5) * 4096;           // 5 grps x 4096 B
    for (int k = w; k < 20; k += 4)
      gl_lds16(bg + (k << 10) + lane * 16, dst + (k << 10));
  };
  auto stageH = [&](int c, unsigned char* dst) {
    for (int k = w; k < 49; k += 4) {                  // 3136 slots / 64
      int sl = (k << 6) + lane;
      int hx = sl & 15; hx = hx > 13 ? 13 : hx;        // phantom x-slots clamp
      int r = sl >> 4;                                 // hz*14+hy, < 196
      int hz = (r * 2341) >> 15;                       // r/14
      int hy = r - hz * 14;
      gl_lds16(xg + ((size_t)((hz * 46 + hy) * 46 + hx)) * 128 + c * 16,
               dst + (k << 10));
    }
  };

  stageB(0, 0, BB);
  stageH(0, XH);

  // byte offsets of the 8 m-tiles relative to abase (a<4: +2y rows each;
  // a>=4: +1 z plane (224 slots) then +2y rows)
  const int AOF[8] = {0, 512, 1024, 1536, 3584, 4096, 4608, 5120};

  int t = 0;
  for (int c = 0; c < 8; ++c) {
    const unsigned char* XHc = XH + (c & 1) * 50176;
    for (int s = 0; s < 9; ++s, ++t) {
      __syncthreads();   // drains own vmcnt: step-t buffers are ready
      if (t + 1 < 72) {
        int cn = (s == 8) ? c + 1 : c;
        int sn = (s == 8) ? 0 : s + 1;
        stageB(cn, sn, BB + ((t + 1) & 1) * 20480);    // in flight during compute
      }
      if (s == 0 && c < 7) stageH(c + 1, XH + ((c + 1) & 1) * 50176);

      const unsigned char* BSc = BB + (t & 1) * 20480 + (size_t)lane * 16;
      #pragma unroll
      for (int gg = 0; gg < 5; ++gg) {
        int tb = (s * 5 + gg) << 2;
        int d0 = TAPS.dl16[tb], d1 = TAPS.dl16[tb + 1];
        int d2_ = TAPS.dl16[tb + 2], d3 = TAPS.dl16[tb + 3];
        int dl = (q == 0) ? d0 : (q == 1) ? d1 : (q == 2) ? d2_ : d3;
        const unsigned char* ab = XHc + ((size_t)(abase + dl) << 4);

        s16x8 afr[8];
        #pragma unroll
        for (int a = 0; a < 8; ++a)
          afr[a] = *(const s16x8*)(ab + AOF[a]);

        const unsigned char* bp = BSc + (gg << 12);
        s16x8 bfr[4];
        #pragma unroll
        for (int nt = 0; nt < 4; ++nt)
          bfr[nt] = *(const s16x8*)(bp + (nt << 10));

        #pragma unroll
        for (int a = 0; a < 8; ++a)
          #pragma unroll
          for (int nt = 0; nt < 4; ++nt)
            acc[a][nt] = __builtin_amdgcn_mfma_f32_16x16x32_bf16(
                afr[a], bfr[nt], acc[a][nt], 0, 0, 0);
      }
    }
  }

  // ---- epilogue: D lane map col=lane&15 (och), row=q*4+reg (position) ------
  // row r -> x += (q&1)*4 + reg, y += q>>1 ; m-tile a -> z = 2w+(a>>2),
  // y += 2*(a&3)
  #pragma unroll
  for (int nt = 0; nt < 4; ++nt) {
    size_t cb = (size_t)(b * 64 + nt * 16 + n) * 64000
              + (size_t)(tz * 8 + 2 * w) * 1600
              + (size_t)(ty * 8 + (q >> 1)) * 40
              + (size_t)(tx * 8 + (q & 1) * 4);
    #pragma unroll
    for (int a = 0; a < 8; ++a) {
      float* dst = out + cb + (size_t)(a >> 2) * 1600 + (size_t)(a & 3) * 80;
      *reinterpret_cast<f32x4*>(dst) = acc[a][nt];
    }
  }
}

// ---------------------------------------------------------------------------
extern "C" void kernel_launch(void* const* d_in, const int* in_sizes, int n_in,
                              void* d_out, int out_size, void* d_ws, size_t ws_size,
                              hipStream_t stream) {
  const float* x    = (const float*)d_in[0];  // [2,64,40,40,40]
  const float* scw0 = (const float*)d_in[1];  // [16,16]
  const float* scw1 = (const float*)d_in[2];  // [16,16]
  const float* tpw  = (const float*)d_in[3];  // [8,1280]
  float* out = (float*)d_out;

  unsigned short* Xp  = (unsigned short*)d_ws;                 // 24,918,016 B
  unsigned short* Bwp = Xp + (size_t)2 * 46 * 46 * 46 * 64;    // 1,474,560 B

  prep<<<4232 + NT_PAD, 256, 0, stream>>>(x, scw0, scw1, tpw, Xp, Bwp);
  conv3d<<<256, 256, 0, stream>>>(Xp, Bwp, out);
}

// Round 4
// 291.954 us; speedup vs baseline: 1.1164x; 1.1164x over previous
//
#include <hip/hip_runtime.h>
#include <stdint.h>

// ---------------------------------------------------------------------------
// Equivariant conv = self-connection (folded into center tap) + sparse-tap
// implicit-GEMM bf16 MFMA conv. R4: 256-pos tiles, 2 blocks/CU (75KB LDS,
// halo single-buffered, B double-buffered), scalar-loaded tap table,
// fully-coalesced prep.
// ---------------------------------------------------------------------------

#define NT_REAL 179   // taps with d^2 <= 12 (radial shells vanish beyond r=3.5)
#define NT_PAD  180
#define NGRP    45    // NT_PAD/4 taps per MFMA k-step

typedef short s16x8 __attribute__((ext_vector_type(8)));
typedef float f32x4 __attribute__((ext_vector_type(4)));

struct Taps {
  int n;
  short dl16[NT_PAD];                       // (dz*14+dy)*16 + dx (halo slot offset)
  unsigned char dz[NT_PAD], dy[NT_PAD], dx[NT_PAD];
};
constexpr Taps mk_taps() {
  Taps t{};
  t.n = 0;
  for (int a = 0; a < 7; ++a)
    for (int b = 0; b < 7; ++b)
      for (int c = 0; c < 7; ++c) {
        int d2 = (a-3)*(a-3) + (b-3)*(b-3) + (c-3)*(c-3);
        if (d2 <= 12) {
          t.dz[t.n] = (unsigned char)a; t.dy[t.n] = (unsigned char)b;
          t.dx[t.n] = (unsigned char)c;
          t.dl16[t.n] = (short)((a*14 + b)*16 + c);
          ++t.n;
        }
      }
  for (int i = t.n; i < NT_PAD; ++i) {      // pad tap: zero weights, valid addr
    t.dz[i] = 3; t.dy[i] = 3; t.dx[i] = 3; t.dl16[i] = t.dl16[0];
  }
  return t;
}
__device__ constexpr Taps TAPS = mk_taps();
static_assert(mk_taps().n == NT_REAL, "tap count");

// 4 tap offsets per group packed into one u64 (8B-aligned -> s_load)
struct DL4s { unsigned long long v[NGRP]; };
constexpr DL4s mk_dl4() {
  DL4s d{};
  Taps t = mk_taps();
  for (int g = 0; g < NGRP; ++g) {
    unsigned long long v = 0;
    for (int q = 0; q < 4; ++q)
      v |= (unsigned long long)(unsigned short)t.dl16[g * 4 + q] << (16 * q);
    d.v[g] = v;
  }
  return d;
}
__device__ constexpr DL4s DL4 = mk_dl4();

static __device__ inline unsigned short f2bf(float f) {   // RNE fp32->bf16
  unsigned int u = __float_as_uint(f);
  unsigned int r = u + 0x7FFFu + ((u >> 16) & 1u);
  return (unsigned short)(r >> 16);
}

__device__ __forceinline__ void gl_lds16(const void* g, void* s) {
  // async 16B/lane global->LDS; LDS dest = wave-uniform base + lane*16
  __builtin_amdgcn_global_load_lds(
      (const __attribute__((address_space(1))) void*)g,
      (__attribute__((address_space(3))) void*)s, 16, 0, 0);
}

// ---------------------------------------------------------------------------
// prep: blocks [0,800) = pad/convert x -> Xp interior (borders pre-zeroed by
// hipMemsetAsync); blocks [800,980) = build Bwp.
//   Xp [2][46][46][46][64] bf16 channel-last.
//   Bwp[chunk8][grp45][nt4][q4][n16][j8]: MFMA k = q*8+j <-> (tap=grp*4+q,
//   ich=chunk*8+j); och = nt*16+n. Lane (q,n) fragment at byte (q*16+n)*16.
// ---------------------------------------------------------------------------
__global__ void prep(const float* __restrict__ x, const float* __restrict__ scw0,
                     const float* __restrict__ scw1, const float* __restrict__ tpw,
                     unsigned short* __restrict__ Xp, unsigned short* __restrict__ Bwp) {
  __shared__ float buf[160 * 65];           // pad: transpose buf / build: wsm alias
  int tid = threadIdx.x;

  if (blockIdx.x < 800) {                   // ---- pad/convert (coalesced) ----
    int blk = blockIdx.x;                   // (b*40 + iz)*10 + ystrip
    int ys = blk % 10; int t2 = blk / 10; int iz = t2 % 40; int b = t2 / 40;
    int y0 = ys * 4;
    const float* src = x + (size_t)b * 4096000 + (size_t)iz * 1600 + (size_t)y0 * 40;
    for (int e = tid; e < 64 * 160; e += 256) {
      int ch = e / 160, i = e - ch * 160;
      buf[i * 65 + ch] = src[(size_t)ch * 64000 + i];   // contiguous per ch
    }
    __syncthreads();
    for (int f = tid; f < 160 * 8; f += 256) {
      int i = f >> 3, g = f & 7;
      int yy = i / 40, xx = i - yy * 40;
      s16x8 v;
      #pragma unroll
      for (int j = 0; j < 8; ++j) v[j] = (short)f2bf(buf[i * 65 + g * 8 + j]);
      size_t dst = ((size_t)((b * 46 + iz + 3) * 46 + (y0 + yy + 3)) * 46 + (xx + 3)) * 64
                 + g * 8;
      *reinterpret_cast<s16x8*>(Xp + dst) = v;          // contiguous 16B/lane
    }
    return;
  }

  // ---- build weights ----
  int t = blockIdx.x - 800;                 // 0..179
  float (*wsm)[16][16] = reinterpret_cast<float (*)[16][16]>(buf);

  int dz = TAPS.dz[t], dy = TAPS.dy[t], dx = TAPS.dx[t];
  float fz = dz - 3.0f, fy = dy - 3.0f, fx = dx - 3.0f;
  float d2 = fz*fz + fy*fy + fx*fx;
  float r = sqrtf(d2);

  const float step = 3.5f / 9.0f;
  const float Cc = 1.14136f * 7.38905609893065f;   // 1.14136 * e^2
  float emb[8];
  for (int bb = 0; bb < 8; ++bb) {
    float diff = (r - step * (bb + 1)) / step;
    float t1 = diff + 1.0f, t2 = 1.0f - diff;
    float u1 = (t1 > 0.0f) ? expf(-1.0f / t1) : 0.0f;
    float u2 = (t2 > 0.0f) ? expf(-1.0f / t2) : 0.0f;
    emb[bb] = Cc * u1 * u2;
  }

  int u = tid >> 4, o = tid & 15;
  for (int p = 0; p < 5; ++p) {
    float acc = 0.0f;
    int nidx = (p * 16 + u) * 16 + o;
    for (int bb = 0; bb < 8; ++bb) acc += emb[bb] * tpw[bb * 1280 + nidx];
    wsm[p][u][o] = acc * (1.0f / 343.0f);
  }
  __syncthreads();

  float invr = (d2 > 0.0f) ? (1.7320508075688772f / r) : 0.0f;  // sqrt(3)/r
  float sh[3] = { fz * invr, fy * invr, fx * invr };

  bool center = (dz == 3 && dy == 3 && dx == 3);
  bool padt = (t >= NT_REAL);
  const float c1 = 0.17677669529663687f;   // sqrt(1/32)
  const float c2 = 0.10206207261596575f;   // c1/sqrt(3)
  const float c3 = 0.14433756729740643f;   // 0.25/sqrt(3)
  const float c4 = 0.14433756729740643f;
  const float c5 = 0.10206207261596575f;   // 0.25/sqrt(6)
  const float inv = 0.25f;                 // 1/sqrt(MUL)

  for (int e = tid; e < 4096; e += 256) {
    int ich = e & 63, och = e >> 6;
    float v = 0.0f;
    if (!padt) {
      if (och < 16) {
        if (ich < 16) {                               // scalar->scalar
          v = c1 * wsm[0][ich][och];
          if (center) v += inv * scw0[ich * 16 + och];
        } else {                                      // vector->scalar
          int qq = ich - 16; int uu = qq / 3, ii = qq % 3;
          v = c2 * sh[ii] * wsm[1][uu][och];
        }
      } else {
        int qo = och - 16; int oo = qo / 3, kk = qo % 3;
        if (ich < 16) {                               // scalar->vector
          v = c3 * sh[kk] * wsm[2][ich][oo];
        } else {                                      // vector->vector
          int qi = ich - 16; int uu = qi / 3, ii = qi % 3;
          if (ii == kk) {
            v = c4 * wsm[3][uu][oo];
            if (center) v += inv * scw1[uu * 16 + oo];
          } else {
            int jj = 3 - ii - kk;
            float sgn = (((kk - ii + 3) % 3) == 2) ? 1.0f : -1.0f;
            v = c5 * sgn * sh[jj] * wsm[4][uu][oo];
          }
        }
      }
    }
    int chunk = ich >> 3, j = ich & 7, q = t & 3, grp = t >> 2;
    int nt = och >> 4, n = och & 15;
    size_t idx = (((((size_t)chunk * NGRP + grp) * 4 + nt) * 4 + q) * 16 + n) * 8 + j;
    Bwp[idx] = f2bf(v);
  }
}

// ---------------------------------------------------------------------------
// conv3d: implicit-GEMM. Block = 256 thr (4 waves), tile = 256 output
// positions (4z x 8y x 8x) x 64 och; grid 500 -> 2 blocks/CU (independent
// barrier domains hide each other's stalls). Wave w = z-plane w, 4m x 4n.
// 72 steps (8 ich-chunks x 9 segments of 5 tap-groups). Halo (10x14x16 slots
// x16B = 35840B) single-buffered, staged once per chunk; B segments (20480B)
// double-buffered, staged one step ahead so every end-of-step barrier drain
// is covered by a full compute step. LDS total 76800B -> 2 blocks/CU.
// ---------------------------------------------------------------------------
__global__ __launch_bounds__(256, 2) void conv3d(
    const unsigned short* __restrict__ Xp,   // [2][46][46][46][64] bf16
    const unsigned short* __restrict__ Bwp,  // [8][45][4][4][16][8] bf16
    float* __restrict__ out) {               // [2][64][40][40][40] fp32
  __shared__ __align__(16) unsigned char smem[76800];
  unsigned char* XH = smem;                  // 35840
  unsigned char* BB = smem + 35840;          // 2 x 20480

  int p = blockIdx.x;                        // 0..499
  int b = p / 250; int rem = p - b * 250;
  int tz = rem / 25, ty = (rem / 5) % 5, tx = rem % 5;

  int tid = threadIdx.x;
  int lane = tid & 63;
  int w = tid >> 6;                          // wave 0..3 -> z-plane w
  int q = lane >> 4, n = lane & 15;
  int qs = q << 4;

  const unsigned char* xg = (const unsigned char*)Xp
      + (size_t)(((b * 46 + tz * 4) * 46 + ty * 8) * 46 + tx * 8) * 128;

  // A fragment base slot: z-plane w (z stride 14*16=224), y_rel = n>>3, x = n&7
  int abase = w * 224 + ((n >> 3) << 4) + (n & 7);

  f32x4 acc[4][4];
  #pragma unroll
  for (int a = 0; a < 4; ++a)
    #pragma unroll
    for (int nt = 0; nt < 4; ++nt) acc[a][nt] = f32x4{0.f, 0.f, 0.f, 0.f};

  auto stageB = [&](int c, int s, unsigned char* dst) {
    const unsigned char* bg = (const unsigned char*)Bwp
        + ((size_t)c * NGRP + s * 5) * 4096;           // 5 grps x 4096 B
    for (int k = w; k < 20; k += 4)
      gl_lds16(bg + (k << 10) + lane * 16, dst + (k << 10));
  };
  auto stageH = [&](int c) {                           // 2240 slots / 64 = 35
    for (int k = w; k < 35; k += 4) {
      int sl = (k << 6) + lane;
      int hx = sl & 15; hx = hx > 13 ? 13 : hx;        // phantom x-slots clamp
      int r = sl >> 4;                                 // hz*14+hy, < 140
      int hz = (r * 2341) >> 15;                       // r/14
      int hy = r - hz * 14;
      gl_lds16(xg + ((size_t)((hz * 46 + hy) * 46 + hx)) * 128 + c * 16,
               XH + (k << 10));
    }
  };

  stageB(0, 0, BB);

  int t = 0;
  for (int c = 0; c < 8; ++c) {
    stageH(c);            // prev chunk's end-of-step barrier gated halo reuse
    __syncthreads();      // drain halo (+ B staged during prev step)
    for (int s = 0; s < 9; ++s, ++t) {
      if (t + 1 < 72) {
        int cn = (s == 8) ? c + 1 : c;
        int sn = (s == 8) ? 0 : s + 1;
        stageB(cn, sn, BB + ((t + 1) & 1) * 20480);    // in flight during compute
      }
      const unsigned char* BSc = BB + (t & 1) * 20480 + (size_t)lane * 16;
      #pragma unroll
      for (int gg = 0; gg < 5; ++gg) {
        unsigned long long dlv = DL4.v[s * 5 + gg];    // uniform -> s_load
        int dl = (int)((dlv >> qs) & 0xFFFFull);
        const unsigned char* ab = XH + ((size_t)(abase + dl) << 4);
        s16x8 a0 = *(const s16x8*)(ab);
        s16x8 a1 = *(const s16x8*)(ab + 512);          // +2 y-rows (32 slots)
        s16x8 a2 = *(const s16x8*)(ab + 1024);
        s16x8 a3 = *(const s16x8*)(ab + 1536);
        const unsigned char* bp = BSc + (gg << 12);
        s16x8 b0 = *(const s16x8*)(bp);
        s16x8 b1 = *(const s16x8*)(bp + 1024);
        s16x8 b2 = *(const s16x8*)(bp + 2048);
        s16x8 b3 = *(const s16x8*)(bp + 3072);
        acc[0][0] = __builtin_amdgcn_mfma_f32_16x16x32_bf16(a0, b0, acc[0][0], 0, 0, 0);
        acc[0][1] = __builtin_amdgcn_mfma_f32_16x16x32_bf16(a0, b1, acc[0][1], 0, 0, 0);
        acc[0][2] = __builtin_amdgcn_mfma_f32_16x16x32_bf16(a0, b2, acc[0][2], 0, 0, 0);
        acc[0][3] = __builtin_amdgcn_mfma_f32_16x16x32_bf16(a0, b3, acc[0][3], 0, 0, 0);
        acc[1][0] = __builtin_amdgcn_mfma_f32_16x16x32_bf16(a1, b0, acc[1][0], 0, 0, 0);
        acc[1][1] = __builtin_amdgcn_mfma_f32_16x16x32_bf16(a1, b1, acc[1][1], 0, 0, 0);
        acc[1][2] = __builtin_amdgcn_mfma_f32_16x16x32_bf16(a1, b2, acc[1][2], 0, 0, 0);
        acc[1][3] = __builtin_amdgcn_mfma_f32_16x16x32_bf16(a1, b3, acc[1][3], 0, 0, 0);
        acc[2][0] = __builtin_amdgcn_mfma_f32_16x16x32_bf16(a2, b0, acc[2][0], 0, 0, 0);
        acc[2][1] = __builtin_amdgcn_mfma_f32_16x16x32_bf16(a2, b1, acc[2][1], 0, 0, 0);
        acc[2][2] = __builtin_amdgcn_mfma_f32_16x16x32_bf16(a2, b2, acc[2][2], 0, 0, 0);
        acc[2][3] = __builtin_amdgcn_mfma_f32_16x16x32_bf16(a2, b3, acc[2][3], 0, 0, 0);
        acc[3][0] = __builtin_amdgcn_mfma_f32_16x16x32_bf16(a3, b0, acc[3][0], 0, 0, 0);
        acc[3][1] = __builtin_amdgcn_mfma_f32_16x16x32_bf16(a3, b1, acc[3][1], 0, 0, 0);
        acc[3][2] = __builtin_amdgcn_mfma_f32_16x16x32_bf16(a3, b2, acc[3][2], 0, 0, 0);
        acc[3][3] = __builtin_amdgcn_mfma_f32_16x16x32_bf16(a3, b3, acc[3][3], 0, 0, 0);
      }
      __syncthreads();    // end-of-step: drains next B stage, gates buffer reuse
    }
  }

  // ---- epilogue: D lane map col=lane&15 (och), row=q*4+reg (position) ------
  // row -> x += (q&1)*4 + reg, y += q>>1 ; m-tile a -> y += 2a ; z = w
  #pragma unroll
  for (int nt = 0; nt < 4; ++nt) {
    size_t cb = (size_t)(b * 64 + nt * 16 + n) * 64000
              + (size_t)(tz * 4 + w) * 1600
              + (size_t)(tx * 8 + (q & 1) * 4);
    #pragma unroll
    for (int a = 0; a < 4; ++a) {
      float* dst = out + cb + (size_t)(ty * 8 + a * 2 + (q >> 1)) * 40;
      *reinterpret_cast<f32x4*>(dst) = acc[a][nt];
    }
  }
}

// ---------------------------------------------------------------------------
extern "C" void kernel_launch(void* const* d_in, const int* in_sizes, int n_in,
                              void* d_out, int out_size, void* d_ws, size_t ws_size,
                              hipStream_t stream) {
  const float* x    = (const float*)d_in[0];  // [2,64,40,40,40]
  const float* scw0 = (const float*)d_in[1];  // [16,16]
  const float* scw1 = (const float*)d_in[2];  // [16,16]
  const float* tpw  = (const float*)d_in[3];  // [8,1280]
  float* out = (float*)d_out;

  unsigned short* Xp  = (unsigned short*)d_ws;                 // 24,918,016 B
  unsigned short* Bwp = Xp + (size_t)2 * 46 * 46 * 46 * 64;    // 1,474,560 B

  hipMemsetAsync(Xp, 0, (size_t)2 * 46 * 46 * 46 * 64 * 2, stream);
  prep<<<800 + NT_PAD, 256, 0, stream>>>(x, scw0, scw1, tpw, Xp, Bwp);
  conv3d<<<500, 256, 0, stream>>>(Xp, Bwp, out);
}

// Round 5
// 236.272 us; speedup vs baseline: 1.3795x; 1.2357x over previous
//
#include <hip/hip_runtime.h>
#include <stdint.h>

// ---------------------------------------------------------------------------
// Equivariant conv = self-connection (folded into center tap) + sparse-tap
// implicit-GEMM bf16 MFMA conv. R5: chunk-major Xp layout (dense halo lines,
// no sector waste) + XCD-contiguous tile swizzle; 2 blocks/CU as in R4.
// ---------------------------------------------------------------------------

#define NT_REAL 179   // taps with d^2 <= 12 (radial shells vanish beyond r=3.5)
#define NT_PAD  180
#define NGRP    45    // NT_PAD/4 taps per MFMA k-step

#define XCH  1557376              // shorts per chunk region: 2*46*46*46*8
#define XCHB ((size_t)XCH * 2)    // bytes per chunk region

typedef short s16x8 __attribute__((ext_vector_type(8)));
typedef float f32x4 __attribute__((ext_vector_type(4)));

struct Taps {
  int n;
  short dl16[NT_PAD];                       // (dz*14+dy)*16 + dx (halo slot offset)
  unsigned char dz[NT_PAD], dy[NT_PAD], dx[NT_PAD];
};
constexpr Taps mk_taps() {
  Taps t{};
  t.n = 0;
  for (int a = 0; a < 7; ++a)
    for (int b = 0; b < 7; ++b)
      for (int c = 0; c < 7; ++c) {
        int d2 = (a-3)*(a-3) + (b-3)*(b-3) + (c-3)*(c-3);
        if (d2 <= 12) {
          t.dz[t.n] = (unsigned char)a; t.dy[t.n] = (unsigned char)b;
          t.dx[t.n] = (unsigned char)c;
          t.dl16[t.n] = (short)((a*14 + b)*16 + c);
          ++t.n;
        }
      }
  for (int i = t.n; i < NT_PAD; ++i) {      // pad tap: zero weights, valid addr
    t.dz[i] = 3; t.dy[i] = 3; t.dx[i] = 3; t.dl16[i] = t.dl16[0];
  }
  return t;
}
__device__ constexpr Taps TAPS = mk_taps();
static_assert(mk_taps().n == NT_REAL, "tap count");

// 4 tap offsets per group packed into one u64 (8B-aligned -> s_load)
struct DL4s { unsigned long long v[NGRP]; };
constexpr DL4s mk_dl4() {
  DL4s d{};
  Taps t = mk_taps();
  for (int g = 0; g < NGRP; ++g) {
    unsigned long long v = 0;
    for (int q = 0; q < 4; ++q)
      v |= (unsigned long long)(unsigned short)t.dl16[g * 4 + q] << (16 * q);
    d.v[g] = v;
  }
  return d;
}
__device__ constexpr DL4s DL4 = mk_dl4();

static __device__ inline unsigned short f2bf(float f) {   // RNE fp32->bf16
  unsigned int u = __float_as_uint(f);
  unsigned int r = u + 0x7FFFu + ((u >> 16) & 1u);
  return (unsigned short)(r >> 16);
}

__device__ __forceinline__ void gl_lds16(const void* g, void* s) {
  // async 16B/lane global->LDS; LDS dest = wave-uniform base + lane*16
  __builtin_amdgcn_global_load_lds(
      (const __attribute__((address_space(1))) void*)g,
      (__attribute__((address_space(3))) void*)s, 16, 0, 0);
}

// ---------------------------------------------------------------------------
// prep: blocks [0,800) = pad/convert x -> Xp interior (borders pre-zeroed by
// hipMemsetAsync); blocks [800,980) = build Bwp.
//   Xp chunk-major: [chunk8][b2][46][46][46][8ch] bf16 (16 B per pos/chunk).
//   Bwp[chunk8][grp45][nt4][q4][n16][j8]: MFMA k = q*8+j <-> (tap=grp*4+q,
//   ich=chunk*8+j); och = nt*16+n. Lane (q,n) fragment at byte (q*16+n)*16.
// ---------------------------------------------------------------------------
__global__ void prep(const float* __restrict__ x, const float* __restrict__ scw0,
                     const float* __restrict__ scw1, const float* __restrict__ tpw,
                     unsigned short* __restrict__ Xp, unsigned short* __restrict__ Bwp) {
  __shared__ float buf[160 * 65];           // pad: transpose buf / build: wsm alias
  int tid = threadIdx.x;

  if (blockIdx.x < 800) {                   // ---- pad/convert (coalesced) ----
    int blk = blockIdx.x;                   // (b*40 + iz)*10 + ystrip
    int ys = blk % 10; int t2 = blk / 10; int iz = t2 % 40; int b = t2 / 40;
    int y0 = ys * 4;
    const float* src = x + (size_t)b * 4096000 + (size_t)iz * 1600 + (size_t)y0 * 40;
    for (int e = tid; e < 64 * 160; e += 256) {
      int ch = e / 160, i = e - ch * 160;
      buf[i * 65 + ch] = src[(size_t)ch * 64000 + i];   // contiguous per ch
    }
    __syncthreads();
    for (int f = tid; f < 160 * 8; f += 256) {
      int i = f >> 3, g = f & 7;
      int yy = i / 40, xx = i - yy * 40;
      s16x8 v;
      #pragma unroll
      for (int j = 0; j < 8; ++j) v[j] = (short)f2bf(buf[i * 65 + g * 8 + j]);
      size_t pos = ((size_t)((b * 46 + iz + 3) * 46 + (y0 + yy + 3)) * 46 + (xx + 3));
      *reinterpret_cast<s16x8*>(Xp + (size_t)g * XCH + pos * 8) = v;
    }
    return;
  }

  // ---- build weights ----
  int t = blockIdx.x - 800;                 // 0..179
  float (*wsm)[16][16] = reinterpret_cast<float (*)[16][16]>(buf);

  int dz = TAPS.dz[t], dy = TAPS.dy[t], dx = TAPS.dx[t];
  float fz = dz - 3.0f, fy = dy - 3.0f, fx = dx - 3.0f;
  float d2 = fz*fz + fy*fy + fx*fx;
  float r = sqrtf(d2);

  const float step = 3.5f / 9.0f;
  const float Cc = 1.14136f * 7.38905609893065f;   // 1.14136 * e^2
  float emb[8];
  for (int bb = 0; bb < 8; ++bb) {
    float diff = (r - step * (bb + 1)) / step;
    float t1 = diff + 1.0f, t2 = 1.0f - diff;
    float u1 = (t1 > 0.0f) ? expf(-1.0f / t1) : 0.0f;
    float u2 = (t2 > 0.0f) ? expf(-1.0f / t2) : 0.0f;
    emb[bb] = Cc * u1 * u2;
  }

  int u = tid >> 4, o = tid & 15;
  for (int p = 0; p < 5; ++p) {
    float acc = 0.0f;
    int nidx = (p * 16 + u) * 16 + o;
    for (int bb = 0; bb < 8; ++bb) acc += emb[bb] * tpw[bb * 1280 + nidx];
    wsm[p][u][o] = acc * (1.0f / 343.0f);
  }
  __syncthreads();

  float invr = (d2 > 0.0f) ? (1.7320508075688772f / r) : 0.0f;  // sqrt(3)/r
  float sh[3] = { fz * invr, fy * invr, fx * invr };

  bool center = (dz == 3 && dy == 3 && dx == 3);
  bool padt = (t >= NT_REAL);
  const float c1 = 0.17677669529663687f;   // sqrt(1/32)
  const float c2 = 0.10206207261596575f;   // c1/sqrt(3)
  const float c3 = 0.14433756729740643f;   // 0.25/sqrt(3)
  const float c4 = 0.14433756729740643f;
  const float c5 = 0.10206207261596575f;   // 0.25/sqrt(6)
  const float inv = 0.25f;                 // 1/sqrt(MUL)

  for (int e = tid; e < 4096; e += 256) {
    int ich = e & 63, och = e >> 6;
    float v = 0.0f;
    if (!padt) {
      if (och < 16) {
        if (ich < 16) {                               // scalar->scalar
          v = c1 * wsm[0][ich][och];
          if (center) v += inv * scw0[ich * 16 + och];
        } else {                                      // vector->scalar
          int qq = ich - 16; int uu = qq / 3, ii = qq % 3;
          v = c2 * sh[ii] * wsm[1][uu][och];
        }
      } else {
        int qo = och - 16; int oo = qo / 3, kk = qo % 3;
        if (ich < 16) {                               // scalar->vector
          v = c3 * sh[kk] * wsm[2][ich][oo];
        } else {                                      // vector->vector
          int qi = ich - 16; int uu = qi / 3, ii = qi % 3;
          if (ii == kk) {
            v = c4 * wsm[3][uu][oo];
            if (center) v += inv * scw1[uu * 16 + oo];
          } else {
            int jj = 3 - ii - kk;
            float sgn = (((kk - ii + 3) % 3) == 2) ? 1.0f : -1.0f;
            v = c5 * sgn * sh[jj] * wsm[4][uu][oo];
          }
        }
      }
    }
    int chunk = ich >> 3, j = ich & 7, q = t & 3, grp = t >> 2;
    int nt = och >> 4, n = och & 15;
    size_t idx = (((((size_t)chunk * NGRP + grp) * 4 + nt) * 4 + q) * 16 + n) * 8 + j;
    Bwp[idx] = f2bf(v);
  }
}

// ---------------------------------------------------------------------------
// conv3d: implicit-GEMM. Block = 256 thr (4 waves), tile = 256 output
// positions (4z x 8y x 8x) x 64 och; grid 512 (12 dummies) -> 2 blocks/CU.
// XCD-contiguous swizzle: XCD j owns tiles [j*64, j*64+64) for halo line
// sharing and B phase coherence in its L2. Wave w = z-plane w, 4m x 4n.
// 72 steps (8 ich-chunks x 9 segments of 5 tap-groups). Halo (10x14x16 slots
// x16B = 35840B, dense chunk-major source) single-buffered per chunk; B
// segments (20480B) double-buffered, staged one step ahead. LDS 76800B.
// ---------------------------------------------------------------------------
__global__ __launch_bounds__(256, 2) void conv3d(
    const unsigned short* __restrict__ Xp,   // [8][2][46][46][46][8] bf16
    const unsigned short* __restrict__ Bwp,  // [8][45][4][4][16][8] bf16
    float* __restrict__ out) {               // [2][64][40][40][40] fp32
  __shared__ __align__(16) unsigned char smem[76800];
  unsigned char* XH = smem;                  // 35840
  unsigned char* BB = smem + 35840;          // 2 x 20480

  int blk = blockIdx.x;                      // 512, 12 dummies
  int p = ((blk & 7) << 6) | (blk >> 3);     // XCD-contiguous tile ranges
  if (p >= 500) return;
  int b = p / 250; int rem = p - b * 250;
  int tz = rem / 25, ty = (rem / 5) % 5, tx = rem % 5;

  int tid = threadIdx.x;
  int lane = tid & 63;
  int w = tid >> 6;                          // wave 0..3 -> z-plane w
  int q = lane >> 4, n = lane & 15;
  int qs = q << 4;

  // dense per-chunk halo source base (16 B per position)
  size_t hbase = (size_t)(((b * 46 + tz * 4) * 46 + ty * 8) * 46 + tx * 8) * 16;

  // A fragment base slot: z-plane w (z stride 14*16=224), y_rel = n>>3, x = n&7
  int abase = w * 224 + ((n >> 3) << 4) + (n & 7);

  f32x4 acc[4][4];
  #pragma unroll
  for (int a = 0; a < 4; ++a)
    #pragma unroll
    for (int nt = 0; nt < 4; ++nt) acc[a][nt] = f32x4{0.f, 0.f, 0.f, 0.f};

  auto stageB = [&](int c, int s, unsigned char* dst) {
    const unsigned char* bg = (const unsigned char*)Bwp
        + ((size_t)c * NGRP + s * 5) * 4096;           // 5 grps x 4096 B
    for (int k = w; k < 20; k += 4)
      gl_lds16(bg + (k << 10) + lane * 16, dst + (k << 10));
  };
  auto stageH = [&](int c) {                           // 2240 slots / 64 = 35
    const unsigned char* xc = (const unsigned char*)Xp + (size_t)c * XCHB + hbase;
    for (int k = w; k < 35; k += 4) {
      int sl = (k << 6) + lane;
      int hx = sl & 15; hx = hx > 13 ? 13 : hx;        // phantom x-slots clamp
      int r = sl >> 4;                                 // hz*14+hy, < 140
      int hz = (r * 2341) >> 15;                       // r/14
      int hy = r - hz * 14;
      gl_lds16(xc + ((size_t)((hz * 46 + hy) * 46 + hx)) * 16, XH + (k << 10));
    }
  };

  stageB(0, 0, BB);

  int t = 0;
  for (int c = 0; c < 8; ++c) {
    stageH(c);            // prev chunk's end-of-step barrier gated halo reuse
    __syncthreads();      // drain halo (+ B staged during prev step)
    for (int s = 0; s < 9; ++s, ++t) {
      if (t + 1 < 72) {
        int cn = (s == 8) ? c + 1 : c;
        int sn = (s == 8) ? 0 : s + 1;
        stageB(cn, sn, BB + ((t + 1) & 1) * 20480);    // in flight during compute
      }
      const unsigned char* BSc = BB + (t & 1) * 20480 + (size_t)lane * 16;
      #pragma unroll
      for (int gg = 0; gg < 5; ++gg) {
        unsigned long long dlv = DL4.v[s * 5 + gg];    // uniform -> s_load
        int dl = (int)((dlv >> qs) & 0xFFFFull);
        const unsigned char* ab = XH + ((size_t)(abase + dl) << 4);
        s16x8 a0 = *(const s16x8*)(ab);
        s16x8 a1 = *(const s16x8*)(ab + 512);          // +2 y-rows (32 slots)
        s16x8 a2 = *(const s16x8*)(ab + 1024);
        s16x8 a3 = *(const s16x8*)(ab + 1536);
        const unsigned char* bp = BSc + (gg << 12);
        s16x8 b0 = *(const s16x8*)(bp);
        s16x8 b1 = *(const s16x8*)(bp + 1024);
        s16x8 b2 = *(const s16x8*)(bp + 2048);
        s16x8 b3 = *(const s16x8*)(bp + 3072);
        acc[0][0] = __builtin_amdgcn_mfma_f32_16x16x32_bf16(a0, b0, acc[0][0], 0, 0, 0);
        acc[0][1] = __builtin_amdgcn_mfma_f32_16x16x32_bf16(a0, b1, acc[0][1], 0, 0, 0);
        acc[0][2] = __builtin_amdgcn_mfma_f32_16x16x32_bf16(a0, b2, acc[0][2], 0, 0, 0);
        acc[0][3] = __builtin_amdgcn_mfma_f32_16x16x32_bf16(a0, b3, acc[0][3], 0, 0, 0);
        acc[1][0] = __builtin_amdgcn_mfma_f32_16x16x32_bf16(a1, b0, acc[1][0], 0, 0, 0);
        acc[1][1] = __builtin_amdgcn_mfma_f32_16x16x32_bf16(a1, b1, acc[1][1], 0, 0, 0);
        acc[1][2] = __builtin_amdgcn_mfma_f32_16x16x32_bf16(a1, b2, acc[1][2], 0, 0, 0);
        acc[1][3] = __builtin_amdgcn_mfma_f32_16x16x32_bf16(a1, b3, acc[1][3], 0, 0, 0);
        acc[2][0] = __builtin_amdgcn_mfma_f32_16x16x32_bf16(a2, b0, acc[2][0], 0, 0, 0);
        acc[2][1] = __builtin_amdgcn_mfma_f32_16x16x32_bf16(a2, b1, acc[2][1], 0, 0, 0);
        acc[2][2] = __builtin_amdgcn_mfma_f32_16x16x32_bf16(a2, b2, acc[2][2], 0, 0, 0);
        acc[2][3] = __builtin_amdgcn_mfma_f32_16x16x32_bf16(a2, b3, acc[2][3], 0, 0, 0);
        acc[3][0] = __builtin_amdgcn_mfma_f32_16x16x32_bf16(a3, b0, acc[3][0], 0, 0, 0);
        acc[3][1] = __builtin_amdgcn_mfma_f32_16x16x32_bf16(a3, b1, acc[3][1], 0, 0, 0);
        acc[3][2] = __builtin_amdgcn_mfma_f32_16x16x32_bf16(a3, b2, acc[3][2], 0, 0, 0);
        acc[3][3] = __builtin_amdgcn_mfma_f32_16x16x32_bf16(a3, b3, acc[3][3], 0, 0, 0);
      }
      __syncthreads();    // end-of-step: drains next B stage, gates buffer reuse
    }
  }

  // ---- epilogue: D lane map col=lane&15 (och), row=q*4+reg (position) ------
  // row -> x += (q&1)*4 + reg, y += q>>1 ; m-tile a -> y += 2a ; z = w
  #pragma unroll
  for (int nt = 0; nt < 4; ++nt) {
    size_t cb = (size_t)(b * 64 + nt * 16 + n) * 64000
              + (size_t)(tz * 4 + w) * 1600
              + (size_t)(tx * 8 + (q & 1) * 4);
    #pragma unroll
    for (int a = 0; a < 4; ++a) {
      float* dst = out + cb + (size_t)(ty * 8 + a * 2 + (q >> 1)) * 40;
      *reinterpret_cast<f32x4*>(dst) = acc[a][nt];
    }
  }
}

// ---------------------------------------------------------------------------
extern "C" void kernel_launch(void* const* d_in, const int* in_sizes, int n_in,
                              void* d_out, int out_size, void* d_ws, size_t ws_size,
                              hipStream_t stream) {
  const float* x    = (const float*)d_in[0];  // [2,64,40,40,40]
  const float* scw0 = (const float*)d_in[1];  // [16,16]
  const float* scw1 = (const float*)d_in[2];  // [16,16]
  const float* tpw  = (const float*)d_in[3];  // [8,1280]
  float* out = (float*)d_out;

  unsigned short* Xp  = (unsigned short*)d_ws;                 // 24,918,016 B
  unsigned short* Bwp = Xp + (size_t)8 * XCH;                  // 1,474,560 B

  hipMemsetAsync(Xp, 0, (size_t)8 * XCH * 2, stream);
  prep<<<800 + NT_PAD, 256, 0, stream>>>(x, scw0, scw1, tpw, Xp, Bwp);
  conv3d<<<512, 256, 0, stream>>>(Xp, Bwp, out);
}